// Round 7
// baseline (280.668 us; speedup 1.0000x reference)
//
#include <hip/hip_runtime.h>
#include <hip/hip_bf16.h>

#define AS1 __attribute__((address_space(1)))
#define AS3 __attribute__((address_space(3)))

typedef __attribute__((ext_vector_type(8))) short bf16x8;
typedef __attribute__((ext_vector_type(4))) float f32x4;

__device__ __forceinline__ unsigned short f2bf(float f) {
    unsigned int u = __float_as_uint(f);
    u += 0x7fffu + ((u >> 16) & 1u);   // RNE
    return (unsigned short)(u >> 16);
}

__device__ __forceinline__ unsigned int pk2bf(float a, float b) {
    __hip_bfloat162 h = __float22bfloat162_rn(make_float2(a, b));  // v_cvt_pk_bf16_f32
    return *reinterpret_cast<unsigned int*>(&h);
}

__device__ __forceinline__ void gload16(const void* g, void* l) {
    __builtin_amdgcn_global_load_lds((const AS1 unsigned int*)g, (AS3 unsigned int*)l, 16, 0, 0);
}

#define MFMA(a, b, c) __builtin_amdgcn_mfma_f32_16x16x32_bf16(a, b, c, 0, 0, 0)

// ---------------------------------------------------------------- converts
__global__ void cvt_f32_bf16(const float* __restrict__ src, unsigned short* __restrict__ dst, int n4) {
    const int i = blockIdx.x * blockDim.x + threadIdx.x;
    if (i >= n4) return;
    const float4 v = reinterpret_cast<const float4*>(src)[i];
    ushort4 o;
    o.x = f2bf(v.x); o.y = f2bf(v.y); o.z = f2bf(v.z); o.w = f2bf(v.w);
    reinterpret_cast<ushort4*>(dst)[i] = o;
}

// ------------------------------------------------------------- RoPE tables
// combined dual-RoPE angle: (t + floor((t/576)*0.5)) * theta_j, theta_j = 10000^(-j/32)
__global__ void rope_table(float* __restrict__ cosT, float* __restrict__ sinT) {
    const int i = blockIdx.x * 256 + threadIdx.x;  // 2048*32
    const int t = i >> 5, j = i & 31;
    const int fid = t / 576;
    const float p = (float)(t + (fid >> 1));
    const float theta = powf(10000.0f, -(float)j / 32.0f);
    const float ang = p * theta;
    cosT[i] = cosf(ang);
    sinT[i] = sinf(ang);
}

// ------------------------------------------------------------------- GEMM
// 256x128 tile, BK=64, 512 threads (8 waves 2Mx4N), tri-buffered LDS (144 KB),
// 4 phases/K-tile, counted vmcnt(6) (T3+T4), setprio around MFMA (T5).
// MODE 0: A[4096x2048] x W'[6144x2048]^T; z = bx>>4 in {Q,K,V}:
//   Q/K: RoPE fused (Q also pre-scaled by 0.125*log2e) -> [B,H,T,64]
//   V  : V^T -> [B,H,64,T]
// MODE 1: A x Wo^T + bo -> fp32 d_out [4096][2048].
template <int MODE>
__global__ __launch_bounds__(512, 2)
void gemm256(const unsigned short* __restrict__ A,
             const unsigned short* __restrict__ W,
             const float* __restrict__ b0, const float* __restrict__ b1, const float* __restrict__ b2,
             const float* __restrict__ cosT, const float* __restrict__ sinT,
             unsigned short* __restrict__ O0, unsigned short* __restrict__ O1, unsigned short* __restrict__ O2,
             float* __restrict__ Of) {
    constexpr int NT = 32;                       // K / 64
    const int nwg = (MODE == 0) ? 768 : 256;
    const int cpx = nwg >> 3;
    const int orig = blockIdx.x;
    const int newid = (orig & 7) * cpx + (orig >> 3);   // XCD-chunked (nwg % 8 == 0)
    const int by = newid & 15;                   // M-tile (16 of 256)
    const int bx = newid >> 4;                   // N-tile (48 or 16 of 128)

    const int tid = threadIdx.x;
    const int lane = tid & 63;
    const int w = tid >> 6;                      // 0..7
    const int wr = w >> 2, wc = w & 3;           // 2M x 4N
    const int l15 = lane & 15, lg = lane >> 4;
    const int brow = by * 256;
    const int bcol = bx * 128;

    __shared__ unsigned char lds[147456];        // 3 x (A 32KB + B 16KB)

    // staging: per 16KB unit = 1024 chunks of 16B; this thread does 2.
    const int c0 = w * 128 + lane;
    const int c1 = c0 + 64;
    const int r0 = c0 >> 3, k0_ = ((c0 & 7) ^ (r0 & 7)) * 8;   // pre-swizzled source
    const int r1 = c1 >> 3, k1_ = ((c1 & 7) ^ (r1 & 7)) * 8;
    const int dA0 = w * 2048, dA1 = w * 2048 + 1024;           // linear LDS dest

#define STG_A(t_, h_, bp_) do {                                                            \
        gload16(A + (size_t)(brow + (h_)*128 + r0) * 2048 + (t_)*64 + k0_, (bp_) + (h_)*16384 + dA0); \
        gload16(A + (size_t)(brow + (h_)*128 + r1) * 2048 + (t_)*64 + k1_, (bp_) + (h_)*16384 + dA1); \
    } while (0)
#define STG_B(t_, bp_) do {                                                                \
        gload16(W + (size_t)(bcol + r0) * 2048 + (t_)*64 + k0_, (bp_) + 32768 + dA0);      \
        gload16(W + (size_t)(bcol + r1) * 2048 + (t_)*64 + k1_, (bp_) + 32768 + dA1);      \
    } while (0)

    f32x4 acc[8][2] = {};

    const int aswz = (l15 & 7) << 4;             // row&7 == l15&7 for all frag rows
    const int kof0 = (lg * 16) ^ aswz;
    const int kof1 = (64 + lg * 16) ^ aswz;
    const int abase = (wr * 128 + l15) * 128;                                  // + m*2048
    const int bbase = ((wc >> 1) * 64 + (wc & 1) * 16 + l15) * 128 + 32768;    // + n*4096

    {   // prologue: stage tiles 0 and 1
        unsigned char* p0 = lds;
        unsigned char* p1 = lds + 49152;
        STG_A(0, 0, p0); STG_A(0, 1, p0); STG_B(0, p0);
        STG_A(1, 0, p1); STG_A(1, 1, p1); STG_B(1, p1);
    }
    asm volatile("s_waitcnt vmcnt(6)" ::: "memory");   // tile 0 landed; tile 1 in flight
    __syncthreads();

#define MM(mi, m_) do {                                          \
        acc[m_][0] = MFMA(af[mi][0], bfr[0][0], acc[m_][0]);     \
        acc[m_][0] = MFMA(af[mi][1], bfr[0][1], acc[m_][0]);     \
        acc[m_][1] = MFMA(af[mi][0], bfr[1][0], acc[m_][1]);     \
        acc[m_][1] = MFMA(af[mi][1], bfr[1][1], acc[m_][1]);     \
    } while (0)

#define LDA_PAIR(p_) do {                                                         \
        af[0][0] = *(const bf16x8*)(bt + abase + (2*(p_)) * 2048 + kof0);         \
        af[0][1] = *(const bf16x8*)(bt + abase + (2*(p_)) * 2048 + kof1);         \
        af[1][0] = *(const bf16x8*)(bt + abase + (2*(p_)+1) * 2048 + kof0);       \
        af[1][1] = *(const bf16x8*)(bt + abase + (2*(p_)+1) * 2048 + kof1);       \
    } while (0)

#define DO_MFMA(p_) do {                                         \
        __builtin_amdgcn_s_barrier();                            \
        __builtin_amdgcn_s_setprio(1);                           \
        MM(0, 2*(p_)); MM(1, 2*(p_)+1);                          \
        __builtin_amdgcn_s_setprio(0);                           \
        __builtin_amdgcn_s_barrier();                            \
    } while (0)

    for (int t = 0; t < NT; ++t) {
        unsigned char* bt = lds + (t % 3) * 49152;          // compute buffer
        unsigned char* bs = lds + ((t + 2) % 3) * 49152;    // stage target (tile t+2)
        const bool pre = (t + 2 < NT);
        bf16x8 bfr[2][2], af[2][2];

        // P1: B-frags + A m=0,1; stage A-half0(t+2)
        bfr[0][0] = *(const bf16x8*)(bt + bbase + kof0);
        bfr[0][1] = *(const bf16x8*)(bt + bbase + kof1);
        bfr[1][0] = *(const bf16x8*)(bt + bbase + 4096 + kof0);
        bfr[1][1] = *(const bf16x8*)(bt + bbase + 4096 + kof1);
        LDA_PAIR(0);
        if (pre) STG_A(t + 2, 0, bs);
        DO_MFMA(0);

        // P2: A m=2,3; stage A-half1(t+2)
        LDA_PAIR(1);
        if (pre) STG_A(t + 2, 1, bs);
        DO_MFMA(1);

        // P3: A m=4,5; stage B(t+2)
        LDA_PAIR(2);
        if (pre) STG_B(t + 2, bs);
        DO_MFMA(2);

        // P4: A m=6,7; counted wait: tile t+1 (oldest) forced complete,
        // tile t+2's 6 loads stay in flight across the barrier.
        LDA_PAIR(3);
        if (pre) { asm volatile("s_waitcnt vmcnt(6)" ::: "memory"); }
        else     { asm volatile("s_waitcnt vmcnt(0)" ::: "memory"); }
        DO_MFMA(3);
    }
#undef STG_A
#undef STG_B
#undef MM
#undef LDA_PAIR
#undef DO_MFMA

    // ----------------------------------------------------------- epilogue
    if (MODE == 0) {
        const int z = bx >> 4;
        const int bxl = bx & 15;
        const int hh = bxl * 2 + (wc >> 1);
        const int d1 = (wc & 1) * 16 + l15;            // 0..31
        const int cgz = hh * 64 + d1;
        const float* bias = (z == 0) ? b0 : (z == 1 ? b1 : b2);
        const float bv1 = bias[cgz], bv2 = bias[cgz + 32];
        if (z < 2) {
            const float qsc = (z == 0) ? 0.18033688011112042f : 1.0f;  // 0.125*log2(e)
            unsigned short* Ot = (z == 0) ? O0 : O1;
#pragma unroll
            for (int m = 0; m < 8; ++m) {
#pragma unroll
                for (int r = 0; r < 4; ++r) {
                    const int rg = brow + wr * 128 + m * 16 + lg * 4 + r;
                    const int bb = rg >> 11, tt = rg & 2047;
                    const float v1 = acc[m][0][r] + bv1;
                    const float v2 = acc[m][1][r] + bv2;
                    const float c = cosT[tt * 32 + d1];
                    const float s = sinT[tt * 32 + d1];
                    unsigned short* base = Ot + (((size_t)bb * 32 + hh) * 2048 + tt) * 64;
                    base[d1]      = f2bf((v1 * c - v2 * s) * qsc);
                    base[d1 + 32] = f2bf((v2 * c + v1 * s) * qsc);
                }
            }
        } else {
#pragma unroll
            for (int m = 0; m < 8; ++m) {
#pragma unroll
                for (int r = 0; r < 4; ++r) {
                    const int rg = brow + wr * 128 + m * 16 + lg * 4 + r;
                    const int bb = rg >> 11, tt = rg & 2047;
                    unsigned short* Vb = O2 + ((size_t)bb * 32 + hh) * 131072 + tt;
                    Vb[(size_t)d1 * 2048]        = f2bf(acc[m][0][r] + bv1);
                    Vb[(size_t)(d1 + 32) * 2048] = f2bf(acc[m][1][r] + bv2);
                }
            }
        }
    } else {
        const int cg = bcol + (wc >> 1) * 64 + (wc & 1) * 16 + l15;
        const float bv1 = b0[cg], bv2 = b0[cg + 32];
#pragma unroll
        for (int m = 0; m < 8; ++m) {
#pragma unroll
            for (int r = 0; r < 4; ++r) {
                const int rg = brow + wr * 128 + m * 16 + lg * 4 + r;
                Of[(size_t)rg * 2048 + cg]      = acc[m][0][r] + bv1;
                Of[(size_t)rg * 2048 + cg + 32] = acc[m][1][r] + bv2;
            }
        }
    }
}

// -------------------------------------------------------- flash attention
// grid 1024 blocks (= 4/CU), 256 threads = 4 waves. QBLK=64, KVBLK=64, causal
// pairing {p, 31-p}. SWAPPED QK^T: sac = mfma(K,Q) so lane holds q=l15 fixed,
// k = nt*16 + lg*4 + r in-register -> per-lane scalar m/l, 2-stage shuffle
// reduce, packed cvt_pk P-writes (4x ds_write_b64/tile). Q pre-scaled by
// 0.125*log2e in the GEMM epilogue; softmax in log2 domain.
__global__ __launch_bounds__(256, 4)
void attn(const unsigned short* __restrict__ Qg, const unsigned short* __restrict__ Kg,
          const unsigned short* __restrict__ Vtg, unsigned short* __restrict__ Og) {
    const int d0 = blockIdx.x;
    const int xcd = d0 & 7, ii = d0 >> 3;       // ii 0..127: 16 pair-blocks per bh
    const int bh = xcd * 8 + (ii >> 4);         // all 16 blocks of a bh on one XCD
    const int pp = ii & 15;
    const int b = bh >> 5, h = bh & 31;
    const int tid = threadIdx.x;
    const int lane = tid & 63;
    const int w = tid >> 6;
    const int l15 = lane & 15, lg = lane >> 4;

    const unsigned short* Q  = Qg  + (size_t)bh * 131072;
    const unsigned short* K  = Kg  + (size_t)bh * 131072;
    const unsigned short* Vt = Vtg + (size_t)bh * 131072;

    __shared__ unsigned char Ks[2][8192];   // [64 k][64 d] bf16, XOR-swizzled
    __shared__ unsigned char Vs[2][8192];   // V^T [64 d][64 k] bf16, XOR-swizzled
    __shared__ unsigned char Ps[4][2048];   // per-wave P [16 q][64 k] bf16, swizzled

    // staging geometry: 512 16B-chunks per tile each for K, V^T; 2 per thread.
    const int cA = (w << 6) + lane, cB = cA + 256;
    const int rA = cA >> 3, bA_ = (cA & 7) ^ (rA & 7);
    const int rB = cB >> 3, bB_ = (cB & 7) ^ (rB & 7);
    const int dstA = (w << 10);
    const int dstB = 4096 + (w << 10);

#define STAGE(kt_, buf_)                                                          \
    do {                                                                          \
        const int ko = (kt_) * 64;                                                \
        gload16(K  + (size_t)(ko + rA) * 64 + bA_ * 8, Ks[buf_] + dstA);          \
        gload16(K  + (size_t)(ko + rB) * 64 + bB_ * 8, Ks[buf_] + dstB);          \
        gload16(Vt + (size_t)rA * 2048 + ko + bA_ * 8, Vs[buf_] + dstA);          \
        gload16(Vt + (size_t)rB * 2048 + ko + bB_ * 8, Vs[buf_] + dstB);          \
    } while (0)

    const int pbase = l15 * 128;           // P row byte base
    const int pswz = (l15 & 7) << 4;       // XOR swizzle for P row
    const int lg8 = lg * 8;

    for (int pass = 0; pass < 2; ++pass) {
        const int qt = pass ? (31 - pp) : pp;
        const int qbase = qt * 64 + w * 16;

        bf16x8 qf[2];
#pragma unroll
        for (int h2 = 0; h2 < 2; ++h2)
            qf[h2] = *(const bf16x8*)(Q + (size_t)(qbase + l15) * 64 + h2 * 32 + lg * 8);

        f32x4 oacc[4] = {};
        float m = -1e30f;   // per-lane row stats for q = l15 (replicated over lg)
        float l = 0.f;      // per-lane PARTIAL row sum (reduced over lg at end)

        __syncthreads();   // previous pass's readers of Ks/Vs are done
        const int ntiles = qt + 1;
        STAGE(0, 0);

        for (int kt = 0; kt < ntiles; ++kt) {
            const int buf = kt & 1;
            asm volatile("s_waitcnt vmcnt(0)" ::: "memory");
            __syncthreads();
            if (kt + 1 < ntiles) STAGE(kt + 1, buf ^ 1);

            const bool diag = (kt == qt);
            const int ntmax = diag ? w : 3;   // diagonal thinning (wave-uniform)

            // S^T = K Q^T: sac[nt] holds rows k = nt*16+lg*4+r, col q = l15
            f32x4 sac[4] = {};
            __builtin_amdgcn_s_setprio(1);
#pragma unroll
            for (int nt = 0; nt < 4; ++nt) {
                if (nt <= ntmax) {
#pragma unroll
                    for (int h2 = 0; h2 < 2; ++h2) {
                        const int kcol = nt * 16 + l15;
                        const int koff = h2 * 64 + lg * 16;
                        const bf16x8 kf = *(const bf16x8*)(Ks[buf] + kcol * 128 + (koff ^ ((kcol & 7) << 4)));
                        sac[nt] = MFMA(kf, qf[h2], sac[nt]);
                    }
                }
            }
            __builtin_amdgcn_s_setprio(0);

            // causal mask: only the nt == w sub-tile of the diagonal tile
            if (diag) {
#pragma unroll
                for (int nt = 0; nt < 4; ++nt) {
                    if (nt == w) {
#pragma unroll
                        for (int r = 0; r < 4; ++r)
                            if (lg * 4 + r > l15) sac[nt][r] = -1e30f;
                    }
                }
            }

            // row max: in-lane tree + 2-stage cross-lg shuffle
            float pm = -1e30f;
#pragma unroll
            for (int nt = 0; nt < 4; ++nt) {
                if (nt <= ntmax) {
#pragma unroll
                    for (int r = 0; r < 4; ++r) pm = fmaxf(pm, sac[nt][r]);
                }
            }
            pm = fmaxf(pm, __shfl_xor(pm, 16));
            pm = fmaxf(pm, __shfl_xor(pm, 32));

            // defer-max (T13, log2 units): rescale only if max grew by > 8
            if (!__all(pm - m <= 8.0f)) {
                const float mn = fmaxf(m, pm);
                const float sc = exp2f(m - mn);
                m = mn;
                l *= sc;
                float scp[4];
#pragma unroll
                for (int r = 0; r < 4; ++r) scp[r] = __shfl(sc, (lg << 2) + r);
#pragma unroll
                for (int dt = 0; dt < 4; ++dt)
#pragma unroll
                    for (int r = 0; r < 4; ++r) oacc[dt][r] *= scp[r];
            }

            // P = exp2(S - m), packed bf16 x4 along k, one ds_write_b64 per nt
#pragma unroll
            for (int nt = 0; nt < 4; ++nt) {
                unsigned long long pk = 0;
                if (nt <= ntmax) {
                    const float p0 = exp2f(sac[nt][0] - m);
                    const float p1 = exp2f(sac[nt][1] - m);
                    const float p2 = exp2f(sac[nt][2] - m);
                    const float p3 = exp2f(sac[nt][3] - m);
                    l += (p0 + p1) + (p2 + p3);
                    pk = ((unsigned long long)pk2bf(p2, p3) << 32) | pk2bf(p0, p1);
                }
                *(unsigned long long*)(Ps[w] + pbase + ((nt * 32 + lg8) ^ pswz)) = pk;
            }

            asm volatile("s_waitcnt lgkmcnt(0)" ::: "memory");
            __builtin_amdgcn_sched_barrier(0);

            // O += P V  (skip upper 32-k half when diagonal thinning allows)
            const int h2max = (ntmax >= 2) ? 1 : 0;
            __builtin_amdgcn_s_setprio(1);
#pragma unroll
            for (int h2 = 0; h2 < 2; ++h2) {
                if (h2 > h2max) continue;
                const int koff = h2 * 64 + lg * 16;
                const bf16x8 pf = *(const bf16x8*)(Ps[w] + pbase + (koff ^ pswz));
#pragma unroll
                for (int dt = 0; dt < 4; ++dt) {
                    const int dcol = dt * 16 + l15;
                    const bf16x8 vf = *(const bf16x8*)(Vs[buf] + dcol * 128 + (koff ^ ((dcol & 7) << 4)));
                    oacc[dt] = MFMA(pf, vf, oacc[dt]);
                }
            }
            __builtin_amdgcn_s_setprio(0);
        }

        // epilogue: full row sum, broadcast to PV layout, divide, store
        float lf = l;
        lf += __shfl_xor(lf, 16);
        lf += __shfl_xor(lf, 32);
        float lq[4];
#pragma unroll
        for (int r = 0; r < 4; ++r) lq[r] = __shfl(lf, (lg << 2) + r);
#pragma unroll
        for (int dt = 0; dt < 4; ++dt) {
#pragma unroll
            for (int r = 0; r < 4; ++r) {
                const int t = qbase + lg * 4 + r;
                const float v = oacc[dt][r] / lq[r];
                Og[(size_t)(b * 2048 + t) * 2048 + h * 64 + dt * 16 + l15] = f2bf(v);
            }
        }
    }
#undef STAGE
}

// ------------------------------------------------------------------ launch
extern "C" void kernel_launch(void* const* d_in, const int* in_sizes, int n_in,
                              void* d_out, int out_size, void* d_ws, size_t ws_size,
                              hipStream_t stream) {
    const float* hs = (const float*)d_in[0];
    const float* Wq = (const float*)d_in[1];
    const float* bq = (const float*)d_in[2];
    const float* Wk = (const float*)d_in[3];
    const float* bk = (const float*)d_in[4];
    const float* Wv = (const float*)d_in[5];
    const float* bv = (const float*)d_in[6];
    const float* Wo = (const float*)d_in[7];
    const float* bo = (const float*)d_in[8];
    float* out = (float*)d_out;

    char* ws = (char*)d_ws;
    unsigned short* Xb = (unsigned short*)ws;                  // 16 MB  [4096][2048] bf16
    unsigned short* Wb = (unsigned short*)(ws + (16u << 20));  // 32 MB  [4][2048][2048] bf16 (W' = [Wq;Wk;Wv;Wo])
    unsigned short* Qb = (unsigned short*)(ws + (48u << 20));  // 16 MB  [B,H,T,64]
    unsigned short* Kb = (unsigned short*)(ws + (64u << 20));  // 16 MB  [B,H,T,64]
    unsigned short* Vtb = (unsigned short*)(ws + (80u << 20)); // 16 MB  [B,H,64,T]  (V^T)
    unsigned short* Ob = Xb;                                   // alias: X dead after QKV GEMM
    float* cosT = (float*)(ws + (96u << 20));                  // 256 KB
    float* sinT = cosT + 65536;                                // 256 KB

    cvt_f32_bf16<<<8192, 256, 0, stream>>>(hs, Xb, 2097152);
    cvt_f32_bf16<<<4096, 256, 0, stream>>>(Wq, Wb + (size_t)0 * 4194304, 1048576);
    cvt_f32_bf16<<<4096, 256, 0, stream>>>(Wk, Wb + (size_t)1 * 4194304, 1048576);
    cvt_f32_bf16<<<4096, 256, 0, stream>>>(Wv, Wb + (size_t)2 * 4194304, 1048576);
    cvt_f32_bf16<<<4096, 256, 0, stream>>>(Wo, Wb + (size_t)3 * 4194304, 1048576);
    rope_table<<<256, 256, 0, stream>>>(cosT, sinT);

    // fused QKV GEMM (N = 6144)
    gemm256<0><<<dim3(768), 512, 0, stream>>>(Xb, Wb, bq, bk, bv, cosT, sinT, Qb, Kb, Vtb, nullptr);

    attn<<<dim3(1024), 256, 0, stream>>>(Qb, Kb, Vtb, Ob);

    gemm256<1><<<dim3(256), 512, 0, stream>>>(Ob, Wb + (size_t)3 * 4194304, bo, bo, bo,
                                              cosT, sinT, nullptr, nullptr, nullptr, out);
}